// Round 4
// baseline (13858.675 us; speedup 1.0000x reference)
//
#include <hip/hip_runtime.h>
#include <hip/hip_bf16.h>

#define V  32000
#define B  32
#define T  128
#define L  48
#define NBLK 256

typedef __attribute__((ext_vector_type(8))) short bf16x8;
typedef __attribute__((ext_vector_type(4))) float f32x4;

#define MFMA16(a, b, c) __builtin_amdgcn_mfma_f32_16x16x32_bf16(a, b, c, 0, 0, 0)

// ---------- f32 -> (bf16 hi, bf16 lo) split, RNE ----------
__device__ __forceinline__ void split1(float f, unsigned short* hi, unsigned short* lo) {
    unsigned u  = __float_as_uint(f);
    unsigned uh = u + (0x7FFFu + ((u >> 16) & 1u));
    unsigned short hs = (unsigned short)(uh >> 16);
    float hf = __uint_as_float(((unsigned)hs) << 16);
    float l  = f - hf;
    unsigned ul = __float_as_uint(l);
    ul += 0x7FFFu + ((ul >> 16) & 1u);
    *hi = hs;
    *lo = (unsigned short)(ul >> 16);
}

__device__ __forceinline__ void split8(const float* __restrict__ p, bf16x8& hi, bf16x8& lo) {
    float4 w0 = reinterpret_cast<const float4*>(p)[0];
    float4 w1 = reinterpret_cast<const float4*>(p)[1];
    float w[8] = {w0.x, w0.y, w0.z, w0.w, w1.x, w1.y, w1.z, w1.w};
    #pragma unroll
    for (int i = 0; i < 8; ++i) {
        unsigned u  = __float_as_uint(w[i]);
        unsigned uh = u + (0x7FFFu + ((u >> 16) & 1u));
        unsigned short hs = (unsigned short)(uh >> 16);
        float hf = __uint_as_float(((unsigned)hs) << 16);
        float l  = w[i] - hf;
        unsigned ul = __float_as_uint(l);
        ul += 0x7FFFu + ((ul >> 16) & 1u);
        hi[i] = (short)hs;
        lo[i] = (short)(ul >> 16);
    }
}

__device__ __forceinline__ float sigmoidf_(float x) { return 1.f / (1.f + expf(-x)); }

__device__ __forceinline__ void fma4(float4& a, const float4 w, const float4 x) {
    a.x = fmaf(w.x, x.x, a.x); a.y = fmaf(w.y, x.y, a.y);
    a.z = fmaf(w.z, x.z, a.z); a.w = fmaf(w.w, x.w, a.w);
}

// ---------- device-scope grid barrier (sense via generation counter) ----------
__device__ __forceinline__ void gbar(unsigned* bar) {
    __syncthreads();
    if (threadIdx.x == 0) {
        __threadfence();   // release all prior writes to device scope
        unsigned g = __hip_atomic_load(&bar[1], __ATOMIC_RELAXED, __HIP_MEMORY_SCOPE_AGENT);
        unsigned a = __hip_atomic_fetch_add(&bar[0], 1u, __ATOMIC_ACQ_REL, __HIP_MEMORY_SCOPE_AGENT);
        if (a == NBLK - 1u) {
            __hip_atomic_store(&bar[0], 0u, __ATOMIC_RELAXED, __HIP_MEMORY_SCOPE_AGENT);
            __hip_atomic_store(&bar[1], g + 1u, __ATOMIC_RELEASE, __HIP_MEMORY_SCOPE_AGENT);
        } else {
            while (__hip_atomic_load(&bar[1], __ATOMIC_ACQUIRE, __HIP_MEMORY_SCOPE_AGENT) == g)
                __builtin_amdgcn_s_sleep(2);
        }
        __threadfence();   // acquire side
    }
    __syncthreads();
}

__global__ void __launch_bounds__(256) decoder_persistent(
    const int* __restrict__ inputs, const float* __restrict__ context,
    const float* __restrict__ enc, const float* __restrict__ emb,
    const float* __restrict__ Wih, const float* __restrict__ Whh,
    const float* __restrict__ bih, const float* __restrict__ bhh,
    const float* __restrict__ linW, const float* __restrict__ linb,
    const float* __restrict__ attnW, const float* __restrict__ attnb,
    float* __restrict__ out,
    unsigned short* __restrict__ Whi, unsigned short* __restrict__ Wlo,
    float* __restrict__ energies,
    float* __restrict__ ctx0buf, float* __restrict__ ctx1buf,
    float* __restrict__ h0buf, float* __restrict__ h1buf,
    unsigned short* __restrict__ Xlhi0, unsigned short* __restrict__ Xllo0,
    unsigned short* __restrict__ Xlhi1, unsigned short* __restrict__ Xllo1,
    float* __restrict__ Pm, int* __restrict__ Pa, float* __restrict__ Ps,
    float* __restrict__ lse_buf, unsigned* __restrict__ bar)
{
    const int bk = blockIdx.x, tid = threadIdx.x;
    __shared__ float red[256];
    __shared__ float sM[32];  __shared__ int sA[32];
    __shared__ float s8m[32][8]; __shared__ int s8a[32][8]; __shared__ float s8s[32][8];
    __shared__ float GI[6][32], GH[6][32];
    __shared__ float Lm[4][32], Ls[4][32]; __shared__ int La[4][32];
    __shared__ float hrow[512], aw[128];

    // ================= setup =================
    // (a) presplit linW -> Whi/Wlo (grid-stride, linear layout [col][k])
    for (long i = (long)bk * 256 + tid; i < (long)V * 128; i += (long)NBLK * 256) {
        bf16x8 h8, l8;
        split8(linW + i * 8, h8, l8);
        *(bf16x8*)(Whi + i * 8) = h8;
        *(bf16x8*)(Wlo + i * 8) = l8;
    }
    // (b) energies = enc @ attn_W^T + attn_b : 1024 vjobs (rb 0..127, cb 0..7)
    for (int p = 0; p < 4; ++p) {
        int vj = bk + p * NBLK;
        int rb = vj >> 3, cb = vj & 7;
        int wave = tid >> 6, lane = tid & 63;
        int col = cb * 64 + wave * 16 + (lane & 15);
        int kg  = (lane >> 4) * 8;
        int arow0 = rb * 32 + (lane & 15);
        f32x4 acc0 = {0.f,0.f,0.f,0.f}, acc1 = {0.f,0.f,0.f,0.f};
        for (int k0 = 0; k0 < 512; k0 += 32) {
            bf16x8 bh, bl;   split8(attnW + (size_t)col * 512 + k0 + kg, bh, bl);
            bf16x8 a0h, a0l; split8(enc + (size_t)arow0 * 512 + k0 + kg, a0h, a0l);
            bf16x8 a1h, a1l; split8(enc + (size_t)(arow0 + 16) * 512 + k0 + kg, a1h, a1l);
            acc0 = MFMA16(a0h, bh, acc0);  acc1 = MFMA16(a1h, bh, acc1);
            acc0 = MFMA16(a0l, bh, acc0);  acc1 = MFMA16(a1l, bh, acc1);
            acc0 = MFMA16(a0h, bl, acc0);  acc1 = MFMA16(a1h, bl, acc1);
        }
        float bias = attnb[col];
        int r0 = (lane >> 4) * 4;
        #pragma unroll
        for (int i = 0; i < 4; ++i) {
            int row = rb * 32 + r0 + i;
            energies[(size_t)row * 512 + col]        = acc0[i] + bias;
            energies[(size_t)(row + 16) * 512 + col] = acc1[i] + bias;
        }
    }
    // (c) init: ctx0, Xl[0].ctx, h0 = 0
    {
        int idx = bk * 256 + tid;
        if (idx < B * 512) {
            int b = idx >> 9, j = idx & 511;
            float c = context[b * 512 + j];
            ctx0buf[b * 512 + j] = c;
            split1(c, &Xlhi0[b * 1024 + 512 + j], &Xllo0[b * 1024 + 512 + j]);
            h0buf[b * 512 + j] = 0.f;
        }
    }
    gbar(bar);

    // ================= decode loop =================
    for (int t = 0; t < L; ++t) {
        const int r = t & 1;
        float* h_r = r ? h1buf : h0buf;      float* h_n = r ? h0buf : h1buf;
        float* ctx_r = r ? ctx1buf : ctx0buf; float* ctx_n = r ? ctx0buf : ctx1buf;
        unsigned short* Xlhi_r = r ? Xlhi1 : Xlhi0;  unsigned short* Xllo_r = r ? Xllo1 : Xllo0;
        unsigned short* Xlhi_n = r ? Xlhi0 : Xlhi1;  unsigned short* Xllo_n = r ? Xllo0 : Xllo1;

        // ---- phase AC: finalize(t-1) reduce (redundant per block) + GRU(t) ----
        if (t == 0) {
            if (tid < 32) sA[tid] = inputs[tid];
            __syncthreads();
        } else {
            int b = tid >> 3, q = tid & 7;
            float m = -INFINITY; int a = 0x7fffffff;
            for (int i = q; i < 500; i += 8) {
                float om = Pm[b * 500 + i]; int oa = Pa[b * 500 + i];
                if (om > m || (om == m && oa < a)) { m = om; a = oa; }
            }
            s8m[b][q] = m; s8a[b][q] = a;
            __syncthreads();
            if (q == 0) {
                #pragma unroll
                for (int i = 1; i < 8; ++i) {
                    float om = s8m[b][i]; int oa = s8a[b][i];
                    if (om > m || (om == m && oa < a)) { m = om; a = oa; }
                }
                sM[b] = m; sA[b] = a;
            }
            __syncthreads();
            float Mb = sM[b];
            float S = 0.f;
            for (int i = q; i < 500; i += 8) S += Ps[b * 500 + i] * expf(Pm[b * 500 + i] - Mb);
            s8s[b][q] = S;
            __syncthreads();
            if (q == 0 && bk == 0) {
                float St = 0.f;
                #pragma unroll
                for (int i = 0; i < 8; ++i) St += s8s[b][i];
                lse_buf[b * L + (t - 1)] = Mb + logf(St);
            }
            __syncthreads();
        }
        // GRU: exact f32 dots; block bk owns cols j = bk*2, bk*2+1
        {
            int idx = tid >> 5, b = tid & 31;
            if (idx < 6) {
                int g = idx % 3, cj = idx / 3;
                int j = bk * 2 + cj, gcol = g * 512 + j;
                const float4* w1 = (const float4*)(Wih + (size_t)gcol * 1024);
                const float4* w2 = (const float4*)(Wih + (size_t)gcol * 1024 + 512);
                const float4* w3 = (const float4*)(Whh + (size_t)gcol * 512);
                const float4* ev = (const float4*)(emb + (size_t)sA[b] * 512);
                const float4* cv = (const float4*)(ctx_r + (size_t)b * 512);
                const float4* hv = (const float4*)(h_r + (size_t)b * 512);
                float4 s0 = {0,0,0,0}, s1 = {0,0,0,0}, s2 = {0,0,0,0}, s3 = {0,0,0,0};
                #pragma unroll 4
                for (int k = 0; k < 128; k += 4) {
                    fma4(s0, w1[k],   ev[k]);   fma4(s1, w1[k+1], ev[k+1]);
                    fma4(s2, w1[k+2], ev[k+2]); fma4(s3, w1[k+3], ev[k+3]);
                }
                #pragma unroll 4
                for (int k = 0; k < 128; k += 4) {
                    fma4(s0, w2[k],   cv[k]);   fma4(s1, w2[k+1], cv[k+1]);
                    fma4(s2, w2[k+2], cv[k+2]); fma4(s3, w2[k+3], cv[k+3]);
                }
                float4 sg;
                sg.x = s0.x + s1.x + s2.x + s3.x; sg.y = s0.y + s1.y + s2.y + s3.y;
                sg.z = s0.z + s1.z + s2.z + s3.z; sg.w = s0.w + s1.w + s2.w + s3.w;
                float gi = (sg.x + sg.y) + (sg.z + sg.w);
                float4 t0 = {0,0,0,0}, t1 = {0,0,0,0}, t2 = {0,0,0,0}, t3 = {0,0,0,0};
                #pragma unroll 4
                for (int k = 0; k < 128; k += 4) {
                    fma4(t0, w3[k],   hv[k]);   fma4(t1, w3[k+1], hv[k+1]);
                    fma4(t2, w3[k+2], hv[k+2]); fma4(t3, w3[k+3], hv[k+3]);
                }
                float4 th;
                th.x = t0.x + t1.x + t2.x + t3.x; th.y = t0.y + t1.y + t2.y + t3.y;
                th.z = t0.z + t1.z + t2.z + t3.z; th.w = t0.w + t1.w + t2.w + t3.w;
                float gh = (th.x + th.y) + (th.z + th.w);
                GI[idx][b] = gi + bih[gcol];
                GH[idx][b] = gh + bhh[gcol];
            }
            __syncthreads();
            if (tid < 64) {
                int b2 = tid & 31, cj = tid >> 5;
                int j = bk * 2 + cj, i0 = cj * 3;
                float rr = sigmoidf_(GI[i0][b2] + GH[i0][b2]);
                float zz = sigmoidf_(GI[i0+1][b2] + GH[i0+1][b2]);
                float nn = tanhf(GI[i0+2][b2] + rr * GH[i0+2][b2]);
                float hn = (1.f - zz) * nn + zz * h_r[(size_t)b2 * 512 + j];
                h_n[(size_t)b2 * 512 + j] = hn;
                split1(hn, &Xlhi_r[(size_t)b2 * 1024 + j], &Xllo_r[(size_t)b2 * 1024 + j]);
            }
        }
        gbar(bar);

        // ---- phase B: score (vjobs 0..499) + attention (vjobs 500..531) ----
        for (int p = 0; p < 3; ++p) {
            int vj = bk + p * NBLK;
            if (vj >= 532) break;
            if (vj < 500) {
                int wave = tid >> 6, lane = tid & 63;
                int c = lane & 15, grp = lane >> 4, kg = grp * 8;
                int col = vj * 64 + wave * 16 + c;
                const unsigned short* x0h = Xlhi_r + (size_t)c * 1024 + kg;
                const unsigned short* x0l = Xllo_r + (size_t)c * 1024 + kg;
                const unsigned short* whp = Whi + (size_t)col * 1024 + kg;
                const unsigned short* wlp = Wlo + (size_t)col * 1024 + kg;
                f32x4 acc0 = {0.f,0.f,0.f,0.f}, acc1 = {0.f,0.f,0.f,0.f};
                #pragma unroll 2
                for (int k0 = 0; k0 < 1024; k0 += 32) {
                    bf16x8 bh  = *(const bf16x8*)(whp + k0);
                    bf16x8 bl  = *(const bf16x8*)(wlp + k0);
                    bf16x8 a0h = *(const bf16x8*)(x0h + k0);
                    bf16x8 a0l = *(const bf16x8*)(x0l + k0);
                    bf16x8 a1h = *(const bf16x8*)(x0h + 16 * 1024 + k0);
                    bf16x8 a1l = *(const bf16x8*)(x0l + 16 * 1024 + k0);
                    acc0 = MFMA16(a0h, bh, acc0);  acc1 = MFMA16(a1h, bh, acc1);
                    acc0 = MFMA16(a0l, bh, acc0);  acc1 = MFMA16(a1l, bh, acc1);
                    acc0 = MFMA16(a0h, bl, acc0);  acc1 = MFMA16(a1h, bl, acc1);
                }
                float bias = linb[col];
                float v[8];
                int r0 = grp * 4;
                #pragma unroll
                for (int i = 0; i < 4; ++i) {
                    v[i]     = acc0[i] + bias;
                    v[i + 4] = acc1[i] + bias;
                    out[(size_t)((r0 + i) * L + t) * V + col]      = v[i];
                    out[(size_t)((r0 + i + 16) * L + t) * V + col] = v[i + 4];
                }
                #pragma unroll
                for (int i = 0; i < 8; ++i) {
                    float m = v[i]; int mc = col;
                    #pragma unroll
                    for (int d = 1; d < 16; d <<= 1) {
                        float om = __shfl_xor(m, d); int oc = __shfl_xor(mc, d);
                        if (om > m || (om == m && oc < mc)) { m = om; mc = oc; }
                    }
                    float s = expf(v[i] - m);
                    #pragma unroll
                    for (int d = 1; d < 16; d <<= 1) s += __shfl_xor(s, d);
                    if (c == 0) {
                        int row = (i < 4) ? r0 + i : r0 + (i - 4) + 16;
                        Lm[wave][row] = m; La[wave][row] = mc; Ls[wave][row] = s;
                    }
                }
                __syncthreads();
                if (tid < 32) {
                    float M = Lm[0][tid]; int a = La[0][tid];
                    #pragma unroll
                    for (int q = 1; q < 4; ++q) {
                        float om = Lm[q][tid]; int oa = La[q][tid];
                        if (om > M || (om == M && oa < a)) { M = om; a = oa; }
                    }
                    float S = 0.f;
                    #pragma unroll
                    for (int q = 0; q < 4; ++q) S += Ls[q][tid] * expf(Lm[q][tid] - M);
                    Pm[tid * 500 + vj] = M;
                    Pa[tid * 500 + vj] = a;
                    Ps[tid * 500 + vj] = S;
                }
            } else {
                int b = vj - 500;
                for (int j = tid; j < 512; j += 256) hrow[j] = h_n[(size_t)b * 512 + j];
                __syncthreads();
                {
                    int tt = tid >> 1, half = tid & 1;
                    const float4* e4 = (const float4*)(energies + ((size_t)(b * T + tt)) * 512 + half * 256);
                    const float4* h4 = (const float4*)(hrow + half * 256);
                    float pdot = 0.f;
                    #pragma unroll 4
                    for (int k = 0; k < 64; ++k) {
                        float4 a = e4[k], cc = h4[k];
                        pdot += a.x * cc.x + a.y * cc.y + a.z * cc.z + a.w * cc.w;
                    }
                    pdot += __shfl_xor(pdot, 1);
                    if (half == 0) aw[tt] = pdot;
                }
                __syncthreads();
                red[tid] = (tid < 128) ? aw[tid] : -INFINITY; __syncthreads();
                for (int s = 128; s > 0; s >>= 1) { if (tid < s) red[tid] = fmaxf(red[tid], red[tid + s]); __syncthreads(); }
                float am = red[0];
                __syncthreads();
                if (tid < 128) { float e = expf(aw[tid] - am); aw[tid] = e; red[tid] = e; } else red[tid] = 0.f;
                __syncthreads();
                for (int s = 128; s > 0; s >>= 1) { if (tid < s) red[tid] += red[tid + s]; __syncthreads(); }
                float asum = red[0];
                __syncthreads();
                float c0 = 0.f, c1 = 0.f;
                for (int tt2 = 0; tt2 < T; ++tt2) {
                    float a = aw[tt2];
                    const float* er = enc + ((size_t)(b * T + tt2)) * 512;
                    c0 += a * er[tid];
                    c1 += a * er[tid + 256];
                }
                c0 /= asum; c1 /= asum;
                ctx_n[(size_t)b * 512 + tid]       = c0;
                ctx_n[(size_t)b * 512 + tid + 256] = c1;
                split1(c0, &Xlhi_n[(size_t)b * 1024 + 512 + tid],       &Xllo_n[(size_t)b * 1024 + 512 + tid]);
                split1(c1, &Xlhi_n[(size_t)b * 1024 + 512 + tid + 256], &Xllo_n[(size_t)b * 1024 + 512 + tid + 256]);
            }
            __syncthreads();
        }
        gbar(bar);
    }

    // ================= epilogue =================
    // lse for t = 47 (blocks 0..31, one b each)
    if (bk < 32) {
        int b = bk;
        float m = -INFINITY;
        for (int i = tid; i < 500; i += 256) m = fmaxf(m, Pm[b * 500 + i]);
        red[tid] = m; __syncthreads();
        for (int s = 128; s > 0; s >>= 1) { if (tid < s) red[tid] = fmaxf(red[tid], red[tid + s]); __syncthreads(); }
        float M = red[0];
        __syncthreads();
        float S = 0.f;
        for (int i = tid; i < 500; i += 256) S += Ps[b * 500 + i] * expf(Pm[b * 500 + i] - M);
        red[tid] = S; __syncthreads();
        for (int s = 128; s > 0; s >>= 1) { if (tid < s) red[tid] += red[tid + s]; __syncthreads(); }
        if (tid == 0) lse_buf[b * L + 47] = M + logf(red[0]);
    }
    gbar(bar);
    // out -= lse (one pass)
    for (long i4 = (long)bk * 256 + tid; i4 < 12288000L; i4 += (long)NBLK * 256) {
        int row = (int)(i4 / 8000);
        float l = lse_buf[row];
        float4* p = (float4*)out + i4;
        float4 v = *p;
        v.x -= l; v.y -= l; v.z -= l; v.w -= l;
        *p = v;
    }
}

extern "C" void kernel_launch(void* const* d_in, const int* in_sizes, int n_in,
                              void* d_out, int out_size, void* d_ws, size_t ws_size,
                              hipStream_t stream) {
    const int*   inputs  = (const int*)d_in[0];
    const float* context = (const float*)d_in[1];
    const float* enc     = (const float*)d_in[3];
    const float* emb     = (const float*)d_in[4];
    const float* Wih     = (const float*)d_in[5];
    const float* Whh     = (const float*)d_in[6];
    const float* bih     = (const float*)d_in[7];
    const float* bhh     = (const float*)d_in[8];
    const float* linW    = (const float*)d_in[9];
    const float* linb    = (const float*)d_in[10];
    const float* attnW   = (const float*)d_in[11];
    const float* attnb   = (const float*)d_in[12];
    float* out = (float*)d_out;

    char* w = (char*)d_ws;
    auto alloc = [&](size_t sz) { char* p = w; w += (sz + 255) & ~(size_t)255; return p; };
    unsigned short* Whi = (unsigned short*)alloc((size_t)V * 1024 * 2);   // 65.5 MB
    unsigned short* Wlo = (unsigned short*)alloc((size_t)V * 1024 * 2);   // 65.5 MB
    float* energies = (float*)alloc((size_t)B * T * 512 * 4);             // 8.39 MB
    float* ctx0buf  = (float*)alloc((size_t)B * 512 * 4);
    float* ctx1buf  = (float*)alloc((size_t)B * 512 * 4);
    float* h0buf    = (float*)alloc((size_t)B * 512 * 4);
    float* h1buf    = (float*)alloc((size_t)B * 512 * 4);
    unsigned short* Xlhi0 = (unsigned short*)alloc((size_t)B * 1024 * 2);
    unsigned short* Xllo0 = (unsigned short*)alloc((size_t)B * 1024 * 2);
    unsigned short* Xlhi1 = (unsigned short*)alloc((size_t)B * 1024 * 2);
    unsigned short* Xllo1 = (unsigned short*)alloc((size_t)B * 1024 * 2);
    float* Pm = (float*)alloc((size_t)B * 500 * 4);
    int*   Pa = (int*)alloc((size_t)B * 500 * 4);
    float* Ps = (float*)alloc((size_t)B * 500 * 4);
    float* lse_buf = (float*)alloc((size_t)B * L * 4);
    unsigned* bar  = (unsigned*)alloc(256);

    hipMemsetAsync(bar, 0, 2 * sizeof(unsigned), stream);

    decoder_persistent<<<NBLK, 256, 0, stream>>>(
        inputs, context, enc, emb, Wih, Whh, bih, bhh, linW, linb, attnW, attnb,
        out, Whi, Wlo, energies, ctx0buf, ctx1buf, h0buf, h1buf,
        Xlhi0, Xllo0, Xlhi1, Xllo1, Pm, Pa, Ps, lse_buf, bar);
}

// Round 5
// 4726.074 us; speedup vs baseline: 2.9324x; 2.9324x over previous
//
#include <hip/hip_runtime.h>
#include <hip/hip_bf16.h>

#define V  32000
#define D  512
#define H  512
#define B  32
#define T  128
#define L  48
#define KLIN 1024
#define KGRU 1536
#define RESCUE_DELTA 0.04f
#define MAXCAND 16

typedef __attribute__((ext_vector_type(8))) short bf16x8;
typedef __attribute__((ext_vector_type(4))) float f32x4;

#define MFMA16(a, b, c) __builtin_amdgcn_mfma_f32_16x16x32_bf16(a, b, c, 0, 0, 0)

// ---------- f32 -> (bf16 hi, bf16 lo) split, RNE ----------
__device__ __forceinline__ void split1(float f, unsigned short* hi, unsigned short* lo) {
    unsigned u  = __float_as_uint(f);
    unsigned uh = u + (0x7FFFu + ((u >> 16) & 1u));
    unsigned short hs = (unsigned short)(uh >> 16);
    float hf = __uint_as_float(((unsigned)hs) << 16);
    float l  = f - hf;
    unsigned ul = __float_as_uint(l);
    ul += 0x7FFFu + ((ul >> 16) & 1u);
    *hi = hs;
    *lo = (unsigned short)(ul >> 16);
}

__device__ __forceinline__ void split8(const float* __restrict__ p, bf16x8& hi, bf16x8& lo) {
    float4 w0 = reinterpret_cast<const float4*>(p)[0];
    float4 w1 = reinterpret_cast<const float4*>(p)[1];
    float w[8] = {w0.x, w0.y, w0.z, w0.w, w1.x, w1.y, w1.z, w1.w};
    #pragma unroll
    for (int i = 0; i < 8; ++i) {
        unsigned u  = __float_as_uint(w[i]);
        unsigned uh = u + (0x7FFFu + ((u >> 16) & 1u));
        unsigned short hs = (unsigned short)(uh >> 16);
        float hf = __uint_as_float(((unsigned)hs) << 16);
        float l  = w[i] - hf;
        unsigned ul = __float_as_uint(l);
        ul += 0x7FFFu + ((ul >> 16) & 1u);
        hi[i] = (short)hs;
        lo[i] = (short)(ul >> 16);
    }
}

// top-2 merge
__device__ __forceinline__ void merge2(float& m1, int& i1, float& m2, int& i2,
                                       float om1, int oi1, float om2, int oi2) {
    bool ogt = (om1 > m1) || (om1 == m1 && oi1 < i1);
    float t1 = ogt ? om1 : m1; int ti1 = ogt ? oi1 : i1;
    float l1 = ogt ? m1 : om1; int li1 = ogt ? i1 : oi1;
    float w2 = ogt ? om2 : m2; int wi2 = ogt ? oi2 : i2;
    bool lgt = (l1 > w2) || (l1 == w2 && li1 < wi2);
    m1 = t1; i1 = ti1;
    m2 = lgt ? l1 : w2; i2 = lgt ? li1 : wi2;
}

// ---------- one-time: linW -> bf16 hi only ----------
__global__ void presplit_lin_hi(const float* __restrict__ src, unsigned short* __restrict__ hi)
{
    long i = (long)blockIdx.x * 256 + threadIdx.x;
    if (i >= (long)V * 128) return;
    bf16x8 h8, l8;
    split8(src + i * 8, h8, l8);
    *(bf16x8*)(hi + i * 8) = h8;
}

// ---------- one-time: split gru weights into combined [1536][1536] K-layout ----------
__global__ void presplit_gru(const float* __restrict__ Wih, const float* __restrict__ Whh,
                             unsigned short* __restrict__ hi, unsigned short* __restrict__ lo)
{
    int i = blockIdx.x * 256 + threadIdx.x;
    if (i >= 1536 * 192) return;
    int col = i / 192, k = (i % 192) * 8;
    const float* src = (k < 1024) ? (Wih + (size_t)col * 1024 + k)
                                  : (Whh + (size_t)col * 512 + (k - 1024));
    bf16x8 h8, l8;
    split8(src, h8, l8);
    *(bf16x8*)(hi + (size_t)col * KGRU + k) = h8;
    *(bf16x8*)(lo + (size_t)col * KGRU + k) = l8;
}

// ---------- init ----------
__global__ void init_state(const int* __restrict__ inputs, const float* __restrict__ context,
                           const float* __restrict__ emb, float* __restrict__ h_t,
                           unsigned short* __restrict__ Xghi, unsigned short* __restrict__ Xglo,
                           unsigned short* __restrict__ Xlhi, unsigned short* __restrict__ Xllo,
                           float* __restrict__ Xf)
{
    int idx = blockIdx.x * 256 + threadIdx.x;   // 0..B*H-1
    int b = idx >> 9, j = idx & 511;
    int tok = inputs[b];
    float e = emb[(size_t)tok * D + j];
    split1(e, &Xghi[b * KGRU + j], &Xglo[b * KGRU + j]);
    float c = context[b * H + j];
    split1(c, &Xghi[b * KGRU + 512 + j], &Xglo[b * KGRU + 512 + j]);
    split1(c, &Xlhi[b * KLIN + 512 + j], &Xllo[b * KLIN + 512 + j]);
    Xf[b * KLIN + 512 + j] = c;
    Xghi[b * KGRU + 1024 + j] = 0;
    Xglo[b * KGRU + 1024 + j] = 0;
    h_t[j * 32 + b] = 0.f;
}

// ---------- energies = enc @ attn_W^T + attn_b (once) ----------
__global__ void __launch_bounds__(256) energies_gemm(
    const float* __restrict__ enc, const float* __restrict__ attnW,
    const float* __restrict__ attnb, float* __restrict__ energies)
{
    int wave = threadIdx.x >> 6, lane = threadIdx.x & 63;
    int col = blockIdx.y * 64 + wave * 16 + (lane & 15);
    int kg  = (lane >> 4) * 8;
    int arow0 = blockIdx.x * 32 + (lane & 15);
    f32x4 acc0 = {0.f,0.f,0.f,0.f}, acc1 = {0.f,0.f,0.f,0.f};
    for (int k0 = 0; k0 < 512; k0 += 32) {
        bf16x8 bh, bl;   split8(attnW + (size_t)col * 512 + k0 + kg, bh, bl);
        bf16x8 a0h, a0l; split8(enc + (size_t)arow0 * 512 + k0 + kg, a0h, a0l);
        bf16x8 a1h, a1l; split8(enc + (size_t)(arow0 + 16) * 512 + k0 + kg, a1h, a1l);
        acc0 = MFMA16(a0h, bh, acc0);  acc1 = MFMA16(a1h, bh, acc1);
        acc0 = MFMA16(a0l, bh, acc0);  acc1 = MFMA16(a1l, bh, acc1);
        acc0 = MFMA16(a0h, bl, acc0);  acc1 = MFMA16(a1h, bl, acc1);
    }
    float bias = attnb[col];
    int r0 = (lane >> 4) * 4;
    #pragma unroll
    for (int i = 0; i < 4; ++i) {
        int row = blockIdx.x * 32 + r0 + i;
        energies[(size_t)row * 512 + col]        = acc0[i] + bias;
        energies[(size_t)(row + 16) * 512 + col] = acc1[i] + bias;
    }
}

// ---------- fused GRU (bf16 hi/lo 3-pass MFMA, 32 blocks x 384) ----------
__global__ void __launch_bounds__(384) gru_fused(
    const unsigned short* __restrict__ Ghi, const unsigned short* __restrict__ Glo,
    const unsigned short* __restrict__ Xghi_r, const unsigned short* __restrict__ Xglo_r,
    unsigned short* __restrict__ Xghi_w, unsigned short* __restrict__ Xglo_w,
    unsigned short* __restrict__ Xlhi_w, unsigned short* __restrict__ Xllo_w,
    float* __restrict__ Xf_w,
    const float* __restrict__ bih, const float* __restrict__ bhh,
    float* __restrict__ h_t)
{
    __shared__ float AI[3][32][16], AH[3][32][16];
    __shared__ float R[32][16], Z[32][16];
    int w = threadIdx.x >> 6, lane = threadIdx.x & 63;
    int g = (w < 3) ? w : w - 3;
    int half = (w >= 3) ? 1 : 0;
    int c = lane & 15, grp = lane >> 4, kg = grp * 8;
    int j = blockIdx.x * 16 + c;
    int gcol = g * 512 + j;
    const unsigned short* wh = Ghi + (size_t)gcol * KGRU;
    const unsigned short* wl = Glo + (size_t)gcol * KGRU;
    const unsigned short* xh = Xghi_r + (size_t)c * KGRU;
    const unsigned short* xl = Xglo_r + (size_t)c * KGRU;
    f32x4 aI0 = {0.f,0.f,0.f,0.f}, aI1 = {0.f,0.f,0.f,0.f};
    f32x4 aH0 = {0.f,0.f,0.f,0.f}, aH1 = {0.f,0.f,0.f,0.f};
    for (int k0 = half * 512; k0 < half * 512 + 512; k0 += 32) {
        bf16x8 bh = *(const bf16x8*)(wh + k0 + kg);
        bf16x8 bl = *(const bf16x8*)(wl + k0 + kg);
        bf16x8 a0h = *(const bf16x8*)(xh + k0 + kg);
        bf16x8 a0l = *(const bf16x8*)(xl + k0 + kg);
        bf16x8 a1h = *(const bf16x8*)(xh + 16 * KGRU + k0 + kg);
        bf16x8 a1l = *(const bf16x8*)(xl + 16 * KGRU + k0 + kg);
        aI0 = MFMA16(a0h, bh, aI0);  aI1 = MFMA16(a1h, bh, aI1);
        aI0 = MFMA16(a0l, bh, aI0);  aI1 = MFMA16(a1l, bh, aI1);
        aI0 = MFMA16(a0h, bl, aI0);  aI1 = MFMA16(a1h, bl, aI1);
    }
    for (int k0 = 1024 + half * 256; k0 < 1024 + half * 256 + 256; k0 += 32) {
        bf16x8 bh = *(const bf16x8*)(wh + k0 + kg);
        bf16x8 bl = *(const bf16x8*)(wl + k0 + kg);
        bf16x8 a0h = *(const bf16x8*)(xh + k0 + kg);
        bf16x8 a0l = *(const bf16x8*)(xl + k0 + kg);
        bf16x8 a1h = *(const bf16x8*)(xh + 16 * KGRU + k0 + kg);
        bf16x8 a1l = *(const bf16x8*)(xl + 16 * KGRU + k0 + kg);
        aH0 = MFMA16(a0h, bh, aH0);  aH1 = MFMA16(a1h, bh, aH1);
        aH0 = MFMA16(a0l, bh, aH0);  aH1 = MFMA16(a1l, bh, aH1);
        aH0 = MFMA16(a0h, bl, aH0);  aH1 = MFMA16(a1h, bl, aH1);
    }
    if (w >= 3) {
        #pragma unroll
        for (int i = 0; i < 4; ++i) {
            AI[g][grp * 4 + i][c] = aI0[i];  AI[g][grp * 4 + i + 16][c] = aI1[i];
            AH[g][grp * 4 + i][c] = aH0[i];  AH[g][grp * 4 + i + 16][c] = aH1[i];
        }
    }
    __syncthreads();
    float gi[8], gh[8];
    if (w < 3) {
        float bi = bih[gcol], bhv = bhh[gcol];
        #pragma unroll
        for (int i = 0; i < 4; ++i) {
            gi[i]     = aI0[i] + AI[g][grp * 4 + i][c]      + bi;
            gi[i + 4] = aI1[i] + AI[g][grp * 4 + i + 16][c] + bi;
            gh[i]     = aH0[i] + AH[g][grp * 4 + i][c]      + bhv;
            gh[i + 4] = aH1[i] + AH[g][grp * 4 + i + 16][c] + bhv;
        }
        if (w == 0) {
            #pragma unroll
            for (int i = 0; i < 8; ++i) {
                int b = (i < 4) ? grp * 4 + i : grp * 4 + (i - 4) + 16;
                R[b][c] = 1.f / (1.f + expf(-(gi[i] + gh[i])));
            }
        } else if (w == 1) {
            #pragma unroll
            for (int i = 0; i < 8; ++i) {
                int b = (i < 4) ? grp * 4 + i : grp * 4 + (i - 4) + 16;
                Z[b][c] = 1.f / (1.f + expf(-(gi[i] + gh[i])));
            }
        }
    }
    __syncthreads();
    if (w == 2) {
        float4 h0 = *(const float4*)(h_t + (size_t)j * 32 + grp * 4);
        float4 h1 = *(const float4*)(h_t + (size_t)j * 32 + grp * 4 + 16);
        float hold[8] = {h0.x, h0.y, h0.z, h0.w, h1.x, h1.y, h1.z, h1.w};
        float hn[8];
        #pragma unroll
        for (int i = 0; i < 8; ++i) {
            int b = (i < 4) ? grp * 4 + i : grp * 4 + (i - 4) + 16;
            float n = tanhf(gi[i] + R[b][c] * gh[i]);
            float z = Z[b][c];
            hn[i] = (1.f - z) * n + z * hold[i];
        }
        *(float4*)(h_t + (size_t)j * 32 + grp * 4)      = make_float4(hn[0], hn[1], hn[2], hn[3]);
        *(float4*)(h_t + (size_t)j * 32 + grp * 4 + 16) = make_float4(hn[4], hn[5], hn[6], hn[7]);
        #pragma unroll
        for (int i = 0; i < 8; ++i) {
            int b = (i < 4) ? grp * 4 + i : grp * 4 + (i - 4) + 16;
            split1(hn[i], &Xlhi_w[(size_t)b * KLIN + j], &Xllo_w[(size_t)b * KLIN + j]);
            Xf_w[(size_t)b * KLIN + j] = hn[i];
            split1(hn[i], &Xghi_w[(size_t)b * KGRU + 1024 + j], &Xglo_w[(size_t)b * KGRU + 1024 + j]);
        }
    }
}

// ---------- score (2-pass, Whi only; blocks 0..499) + attention/ctx (500..531) ----------
__global__ void __launch_bounds__(256) score_attn(
    const unsigned short* __restrict__ Whi, const float* __restrict__ linb,
    const unsigned short* __restrict__ Xlhi_r, const unsigned short* __restrict__ Xllo_r,
    unsigned short* __restrict__ Xlhi_n, unsigned short* __restrict__ Xllo_n,
    float* __restrict__ Xf_n,
    unsigned short* __restrict__ Xghi_n, unsigned short* __restrict__ Xglo_n,
    const float* __restrict__ h_t, const float* __restrict__ energies,
    const float* __restrict__ enc,
    float* __restrict__ out,
    float* __restrict__ Pm, int* __restrict__ Pa,
    float* __restrict__ Pm2, int* __restrict__ Pa2,
    float* __restrict__ Ps, int t)
{
    __shared__ float Lm1[4][32], Lm2[4][32], Ls[4][32];
    __shared__ int   Li1[4][32], Li2[4][32];
    __shared__ float hrow[512], aw[128], red[256];
    int tid = threadIdx.x;
    if (blockIdx.x < 500) {
        int wave = tid >> 6, lane = tid & 63;
        int c = lane & 15, grp = lane >> 4, kg = grp * 8;
        int col = blockIdx.x * 64 + wave * 16 + c;
        const unsigned short* x0h = Xlhi_r + (size_t)c * KLIN + kg;
        const unsigned short* x0l = Xllo_r + (size_t)c * KLIN + kg;
        const unsigned short* whp = Whi + (size_t)col * KLIN + kg;
        f32x4 acc0 = {0.f,0.f,0.f,0.f}, acc1 = {0.f,0.f,0.f,0.f};
        #pragma unroll 4
        for (int k0 = 0; k0 < 1024; k0 += 32) {
            bf16x8 bh  = *(const bf16x8*)(whp + k0);
            bf16x8 a0h = *(const bf16x8*)(x0h + k0);
            bf16x8 a0l = *(const bf16x8*)(x0l + k0);
            bf16x8 a1h = *(const bf16x8*)(x0h + 16 * KLIN + k0);
            bf16x8 a1l = *(const bf16x8*)(x0l + 16 * KLIN + k0);
            acc0 = MFMA16(a0h, bh, acc0);  acc1 = MFMA16(a1h, bh, acc1);
            acc0 = MFMA16(a0l, bh, acc0);  acc1 = MFMA16(a1l, bh, acc1);
        }
        float bias = linb[col];
        float v[8];
        int r0 = grp * 4;
        #pragma unroll
        for (int i = 0; i < 4; ++i) {
            v[i]     = acc0[i] + bias;
            v[i + 4] = acc1[i] + bias;
            out[(size_t)((r0 + i) * L + t) * V + col]      = v[i];
            out[(size_t)((r0 + i + 16) * L + t) * V + col] = v[i + 4];
        }
        // per-row top-2 + sumexp across this block's 64 cols
        #pragma unroll
        for (int i = 0; i < 8; ++i) {
            float m1 = v[i]; int i1 = col; float m2 = -INFINITY; int i2 = 0x7fffffff;
            #pragma unroll
            for (int d = 1; d < 16; d <<= 1) {
                float om1 = __shfl_xor(m1, d); int oi1 = __shfl_xor(i1, d);
                float om2 = __shfl_xor(m2, d); int oi2 = __shfl_xor(i2, d);
                merge2(m1, i1, m2, i2, om1, oi1, om2, oi2);
            }
            float s = expf(v[i] - m1);
            #pragma unroll
            for (int d = 1; d < 16; d <<= 1) s += __shfl_xor(s, d);
            if (c == 0) {
                int row = (i < 4) ? r0 + i : r0 + (i - 4) + 16;
                Lm1[wave][row] = m1; Li1[wave][row] = i1;
                Lm2[wave][row] = m2; Li2[wave][row] = i2;
                Ls[wave][row] = s;
            }
        }
        __syncthreads();
        if (tid < 32) {
            float m1 = Lm1[0][tid]; int i1 = Li1[0][tid];
            float m2 = Lm2[0][tid]; int i2 = Li2[0][tid];
            #pragma unroll
            for (int q = 1; q < 4; ++q)
                merge2(m1, i1, m2, i2, Lm1[q][tid], Li1[q][tid], Lm2[q][tid], Li2[q][tid]);
            float S = 0.f;
            #pragma unroll
            for (int q = 0; q < 4; ++q) S += Ls[q][tid] * expf(Lm1[q][tid] - m1);
            Pm [tid * 500 + blockIdx.x] = m1;
            Pa [tid * 500 + blockIdx.x] = i1;
            Pm2[tid * 500 + blockIdx.x] = m2;
            Pa2[tid * 500 + blockIdx.x] = i2;
            Ps [tid * 500 + blockIdx.x] = S;
        }
    } else {
        int b = blockIdx.x - 500;
        for (int j = tid; j < 512; j += 256) hrow[j] = h_t[(size_t)j * 32 + b];
        __syncthreads();
        {
            int tt = tid >> 1, half = tid & 1;
            const float4* e4 = (const float4*)(energies + ((size_t)(b * T + tt)) * 512 + half * 256);
            const float4* h4 = (const float4*)(hrow + half * 256);
            float p = 0.f;
            #pragma unroll 4
            for (int k = 0; k < 64; ++k) {
                float4 a = e4[k], cc = h4[k];
                p += a.x * cc.x + a.y * cc.y + a.z * cc.z + a.w * cc.w;
            }
            p += __shfl_xor(p, 1);
            if (half == 0) aw[tt] = p;
        }
        __syncthreads();
        red[tid] = (tid < 128) ? aw[tid] : -INFINITY; __syncthreads();
        for (int s = 128; s > 0; s >>= 1) { if (tid < s) red[tid] = fmaxf(red[tid], red[tid + s]); __syncthreads(); }
        float am = red[0];
        __syncthreads();
        if (tid < 128) { float e = expf(aw[tid] - am); aw[tid] = e; red[tid] = e; } else red[tid] = 0.f;
        __syncthreads();
        for (int s = 128; s > 0; s >>= 1) { if (tid < s) red[tid] += red[tid + s]; __syncthreads(); }
        float asum = red[0];
        __syncthreads();
        float c0 = 0.f, c1 = 0.f;
        for (int tt2 = 0; tt2 < T; ++tt2) {
            float a = aw[tt2];
            const float* er = enc + ((size_t)(b * T + tt2)) * 512;
            c0 += a * er[tid];
            c1 += a * er[tid + 256];
        }
        c0 /= asum; c1 /= asum;
        Xf_n[(size_t)b * KLIN + 512 + tid]       = c0;
        Xf_n[(size_t)b * KLIN + 512 + tid + 256] = c1;
        split1(c0, &Xlhi_n[(size_t)b * KLIN + 512 + tid],       &Xllo_n[(size_t)b * KLIN + 512 + tid]);
        split1(c1, &Xlhi_n[(size_t)b * KLIN + 512 + tid + 256], &Xllo_n[(size_t)b * KLIN + 512 + tid + 256]);
        split1(c0, &Xghi_n[(size_t)b * KGRU + 512 + tid],       &Xglo_n[(size_t)b * KGRU + 512 + tid]);
        split1(c1, &Xghi_n[(size_t)b * KGRU + 512 + tid + 256], &Xglo_n[(size_t)b * KGRU + 512 + tid + 256]);
    }
}

// ---------- finalize: lse + exact-rescue argmax + emb gather ----------
__global__ void __launch_bounds__(256) finalize(
    const float* __restrict__ Pm, const int* __restrict__ Pa,
    const float* __restrict__ Pm2, const int* __restrict__ Pa2,
    const float* __restrict__ Ps,
    const float* __restrict__ linW, const float* __restrict__ linb,
    const float* __restrict__ Xf_r, const float* __restrict__ emb,
    unsigned short* __restrict__ Xghi_n, unsigned short* __restrict__ Xglo_n,
    float* __restrict__ lse_buf, int t)
{
    __shared__ float xb[1024];
    __shared__ float sred[256];
    __shared__ int   list[MAXCAND];
    __shared__ float cscore[MAXCAND];
    __shared__ int   ncand_sh, amax_sh;
    int b = blockIdx.x, tid = threadIdx.x;
    for (int j = tid; j < 1024; j += 256) xb[j] = Xf_r[(size_t)b * KLIN + j];
    if (tid == 0) ncand_sh = 0;
    __syncthreads();
    // approx global max
    float m = -INFINITY;
    for (int i = tid; i < 500; i += 256) m = fmaxf(m, Pm[b * 500 + i]);
    sred[tid] = m; __syncthreads();
    for (int s = 128; s > 0; s >>= 1) { if (tid < s) sred[tid] = fmaxf(sred[tid], sred[tid + s]); __syncthreads(); }
    float M = sred[0];
    float thresh = M - RESCUE_DELTA;
    __syncthreads();
    // sumexp + candidate collection (top-2 per block)
    float S = 0.f;
    for (int i = tid; i < 500; i += 256) {
        float pm = Pm[b * 500 + i];
        S += Ps[b * 500 + i] * expf(pm - M);
        if (pm >= thresh) { int p = atomicAdd(&ncand_sh, 1); if (p < MAXCAND) list[p] = Pa[b * 500 + i]; }
        if (Pm2[b * 500 + i] >= thresh) { int p = atomicAdd(&ncand_sh, 1); if (p < MAXCAND) list[p] = Pa2[b * 500 + i]; }
    }
    sred[tid] = S; __syncthreads();
    for (int s = 128; s > 0; s >>= 1) { if (tid < s) sred[tid] += sred[tid + s]; __syncthreads(); }
    if (tid == 0) lse_buf[b * L + t] = M + logf(sred[0]);
    __syncthreads();
    int nc = ncand_sh < MAXCAND ? ncand_sh : MAXCAND;
    // exact f32 dots per candidate (one wave each)
    int wv = tid >> 6, lane = tid & 63;
    for (int ci = wv; ci < nc; ci += 4) {
        int col = list[ci];
        const float* wr = linW + (size_t)col * 1024 + lane * 16;
        const float* xr = xb + lane * 16;
        float s = 0.f;
        #pragma unroll
        for (int jj = 0; jj < 16; jj += 4) {
            float4 a = *(const float4*)(wr + jj);
            s += a.x * xr[jj] + a.y * xr[jj + 1] + a.z * xr[jj + 2] + a.w * xr[jj + 3];
        }
        #pragma unroll
        for (int d = 1; d < 64; d <<= 1) s += __shfl_xor(s, d);
        if (lane == 0) cscore[ci] = s + linb[col];
    }
    __syncthreads();
    if (tid == 0) {
        float bm = -INFINITY; int bi = 0x7fffffff;
        for (int ci = 0; ci < nc; ++ci) {
            float vv = cscore[ci]; int cc = list[ci];
            if (vv > bm || (vv == bm && cc < bi)) { bm = vv; bi = cc; }
        }
        amax_sh = bi;
    }
    __syncthreads();
    int amax = amax_sh;
    for (int j = tid; j < 512; j += 256)
        split1(emb[(size_t)amax * D + j], &Xghi_n[(size_t)b * KGRU + j], &Xglo_n[(size_t)b * KGRU + j]);
}

// ---------- final: out -= lse ----------
__global__ void __launch_bounds__(256) subtract_lse(float* __restrict__ out,
                                                    const float* __restrict__ lse_buf)
{
    long i4 = (long)blockIdx.x * 256 + threadIdx.x;
    int row = (int)(i4 / 8000);
    float l = lse_buf[row];
    float4* p = (float4*)out + i4;
    float4 v = *p;
    v.x -= l; v.y -= l; v.z -= l; v.w -= l;
    *p = v;
}

extern "C" void kernel_launch(void* const* d_in, const int* in_sizes, int n_in,
                              void* d_out, int out_size, void* d_ws, size_t ws_size,
                              hipStream_t stream) {
    const int*   inputs  = (const int*)d_in[0];
    const float* context = (const float*)d_in[1];
    const float* enc     = (const float*)d_in[3];
    const float* emb     = (const float*)d_in[4];
    const float* Wih     = (const float*)d_in[5];
    const float* Whh     = (const float*)d_in[6];
    const float* bih     = (const float*)d_in[7];
    const float* bhh     = (const float*)d_in[8];
    const float* linW    = (const float*)d_in[9];
    const float* linb    = (const float*)d_in[10];
    const float* attnW   = (const float*)d_in[11];
    const float* attnb   = (const float*)d_in[12];
    float* out = (float*)d_out;

    char* w = (char*)d_ws;
    auto alloc = [&](size_t sz) { char* p = w; w += (sz + 255) & ~(size_t)255; return p; };
    unsigned short* Whi = (unsigned short*)alloc((size_t)V * KLIN * 2);      // 65.5 MB
    unsigned short* Ghi = (unsigned short*)alloc((size_t)1536 * KGRU * 2);   // 4.72 MB
    unsigned short* Glo = (unsigned short*)alloc((size_t)1536 * KGRU * 2);
    float* energies = (float*)alloc((size_t)B * T * 512 * 4);                // 8.39 MB
    float* h_t      = (float*)alloc((size_t)H * B * 4);
    unsigned short* Xghi[2]; unsigned short* Xglo[2];
    unsigned short* Xlhi[2]; unsigned short* Xllo[2];
    float* Xf[2];
    for (int q = 0; q < 2; ++q) {
        Xghi[q] = (unsigned short*)alloc((size_t)B * KGRU * 2);
        Xglo[q] = (unsigned short*)alloc((size_t)B * KGRU * 2);
        Xlhi[q] = (unsigned short*)alloc((size_t)B * KLIN * 2);
        Xllo[q] = (unsigned short*)alloc((size_t)B * KLIN * 2);
        Xf[q]   = (float*)alloc((size_t)B * KLIN * 4);
    }
    float* Pm  = (float*)alloc((size_t)B * 500 * 4);
    int*   Pa  = (int*)alloc((size_t)B * 500 * 4);
    float* Pm2 = (float*)alloc((size_t)B * 500 * 4);
    int*   Pa2 = (int*)alloc((size_t)B * 500 * 4);
    float* Ps  = (float*)alloc((size_t)B * 500 * 4);
    float* lse_buf = (float*)alloc((size_t)B * L * 4);

    presplit_lin_hi<<<16000, 256, 0, stream>>>(linW, Whi);
    presplit_gru<<<1152, 256, 0, stream>>>(Wih, Whh, Ghi, Glo);
    init_state<<<64, 256, 0, stream>>>(inputs, context, emb, h_t,
                                       Xghi[0], Xglo[0], Xlhi[0], Xllo[0], Xf[0]);
    energies_gemm<<<dim3(128, 8), 256, 0, stream>>>(enc, attnW, attnb, energies);

    for (int t = 0; t < L; ++t) {
        int r = t & 1, n = (t + 1) & 1;
        gru_fused<<<32, 384, 0, stream>>>(Ghi, Glo, Xghi[r], Xglo[r],
                                          Xghi[n], Xglo[n], Xlhi[r], Xllo[r], Xf[r],
                                          bih, bhh, h_t);
        score_attn<<<532, 256, 0, stream>>>(Whi, linb, Xlhi[r], Xllo[r],
                                            Xlhi[n], Xllo[n], Xf[n],
                                            Xghi[n], Xglo[n],
                                            h_t, energies, enc, out,
                                            Pm, Pa, Pm2, Pa2, Ps, t);
        finalize<<<32, 256, 0, stream>>>(Pm, Pa, Pm2, Pa2, Ps, linW, linb,
                                         Xf[r], emb, Xghi[n], Xglo[n], lse_buf, t);
    }
    subtract_lse<<<48000, 256, 0, stream>>>(out, lse_buf);
}